// Round 2
// 240.889 us; speedup vs baseline: 1.0056x; 1.0056x over previous
//
#include <hip/hip_runtime.h>

#define BB 128
#define FF 512
#define NWAVES 8192            // 2048 blocks * 4 waves
#define STEPS  8               // (BB*FF) / NWAVES rows per wave

// Native clang vector type — required by __builtin_nontemporal_{load,store}.
typedef float v4f __attribute__((ext_vector_type(4)));

// Persistent-wave streaming version. Each wave owns STEPS=8 rows at stride
// NWAVES=8192. Since 8192 = 16*512, j = wid & 511 is CONSTANT per wave
// (weight/ps rows loaded once, reused 8x) and b = (wid>>9) + 16*t.
// Software pipeline: row t+1's hebb/last_out loads are issued before row t's
// reduce/tanh chain, so the streaming-load queue never drains while the wave
// sits in its dependent chain (breaks the load->compute->store convoy of the
// one-shot-wave version). hebb in/out stay nontemporal (zero reuse).
__global__ __launch_bounds__(256) void PlasticLinearRec_kernel(
    const float* __restrict__ input,
    const float* __restrict__ last_out,
    const float* __restrict__ hebb,
    const float* __restrict__ weight,
    const float* __restrict__ ps,
    const float* __restrict__ lr_p,
    float* __restrict__ out,       // B*F
    float* __restrict__ hebb_new)  // B*F*F
{
    const int wave = threadIdx.x >> 6;
    const int lane = threadIdx.x & 63;
    const int wid  = blockIdx.x * 4 + wave;     // 0 .. NWAVES-1
    const int b0   = wid >> 9;                  // 0..15
    const int j    = wid & (FF - 1);            // fixed for all STEPS rows

    const int k0 = lane * 4;
    const int k1 = 256 + lane * 4;

    // weight/ps row j: loaded ONCE, reused for all 8 rows of this wave.
    const int wbase = j * FF;
    const v4f w0 = *(const v4f*)(weight + wbase + k0);
    const v4f w1 = *(const v4f*)(weight + wbase + k1);
    const v4f p0 = *(const v4f*)(ps     + wbase + k0);
    const v4f p1 = *(const v4f*)(ps     + wbase + k1);

    const float lr = lr_p[0];

    size_t       hb    = (size_t)wid * FF;          // hebb row offset (floats)
    const size_t hstep = (size_t)NWAVES * FF;       // row stride in floats
    int          lob   = b0 * FF;                   // last_out/input row offset
    const int    lostep = 16 * FF;

    // Prologue: prefetch row t=0.
    v4f h0 = __builtin_nontemporal_load((const v4f*)(hebb + hb + k0));
    v4f h1 = __builtin_nontemporal_load((const v4f*)(hebb + hb + k1));
    v4f l0 = *(const v4f*)(last_out + lob + k0);
    v4f l1 = *(const v4f*)(last_out + lob + k1);

    #pragma unroll 1   // keep the double-buffer tight: no 8x reg-hoisted unroll
    for (int t = 0; t < STEPS; ++t) {
        // Capture current row's operands, then immediately issue next row's
        // streaming loads so they fly during the reduce/tanh chain.
        const v4f ch0 = h0, ch1 = h1, cl0 = l0, cl1 = l1;
        const size_t hb_c  = hb;
        const int    lob_c = lob;

        hb  += hstep;
        lob += lostep;
        if (t + 1 < STEPS) {
            h0 = __builtin_nontemporal_load((const v4f*)(hebb + hb + k0));
            h1 = __builtin_nontemporal_load((const v4f*)(hebb + hb + k1));
            l0 = *(const v4f*)(last_out + lob + k0);
            l1 = *(const v4f*)(last_out + lob + k1);
        }

        // pre[b,j] partial: acc += lo[k] * (w[j,k] + ps[j,k]*h[b,j,k])
        float acc;
        acc = cl0.x * fmaf(p0.x, ch0.x, w0.x);
        acc = fmaf(cl0.y, fmaf(p0.y, ch0.y, w0.y), acc);
        acc = fmaf(cl0.z, fmaf(p0.z, ch0.z, w0.z), acc);
        acc = fmaf(cl0.w, fmaf(p0.w, ch0.w, w0.w), acc);
        acc = fmaf(cl1.x, fmaf(p1.x, ch1.x, w1.x), acc);
        acc = fmaf(cl1.y, fmaf(p1.y, ch1.y, w1.y), acc);
        acc = fmaf(cl1.z, fmaf(p1.z, ch1.z, w1.z), acc);
        acc = fmaf(cl1.w, fmaf(p1.w, ch1.w, w1.w), acc);

        // 64-lane xor butterfly: every lane ends with the full row sum.
        #pragma unroll
        for (int off = 32; off > 0; off >>= 1)
            acc += __shfl_xor(acc, off, 64);

        const float o = tanhf(acc + input[lob_c + j]);
        const float c = lr * o;

        if (lane == 0) out[lob_c + j] = o;

        // hebb_new = fma(lr*o, lo[k] - o*h, h)
        v4f n0, n1;
        n0.x = fmaf(c, cl0.x - o * ch0.x, ch0.x);
        n0.y = fmaf(c, cl0.y - o * ch0.y, ch0.y);
        n0.z = fmaf(c, cl0.z - o * ch0.z, ch0.z);
        n0.w = fmaf(c, cl0.w - o * ch0.w, ch0.w);
        n1.x = fmaf(c, cl1.x - o * ch1.x, ch1.x);
        n1.y = fmaf(c, cl1.y - o * ch1.y, ch1.y);
        n1.z = fmaf(c, cl1.z - o * ch1.z, ch1.z);
        n1.w = fmaf(c, cl1.w - o * ch1.w, ch1.w);

        __builtin_nontemporal_store(n0, (v4f*)(hebb_new + hb_c + k0));
        __builtin_nontemporal_store(n1, (v4f*)(hebb_new + hb_c + k1));
    }
}

extern "C" void kernel_launch(void* const* d_in, const int* in_sizes, int n_in,
                              void* d_out, int out_size, void* d_ws, size_t ws_size,
                              hipStream_t stream) {
    const float* input    = (const float*)d_in[0];
    const float* last_out = (const float*)d_in[1];
    const float* hebb     = (const float*)d_in[2];
    const float* weight   = (const float*)d_in[3];
    const float* ps       = (const float*)d_in[4];
    const float* lr       = (const float*)d_in[5];

    float* out      = (float*)d_out;            // first B*F floats
    float* hebb_new = out + BB * FF;            // then B*F*F floats

    const int blocks = NWAVES / 4;              // 2048 blocks, 4 waves each

    PlasticLinearRec_kernel<<<blocks, 256, 0, stream>>>(
        input, last_out, hebb, weight, ps, lr, out, hebb_new);
}